// Round 1
// baseline (72.527 us; speedup 1.0000x reference)
//
#include <hip/hip_runtime.h>
#include <hip/hip_bf16.h>
#include <stdint.h>

typedef __attribute__((ext_vector_type(8))) short short8;
typedef __attribute__((ext_vector_type(4))) float f32x4;

#define BSZ 512
#define DFIELD 16384
#define KSPLIT 48
#define KCHUNK 1024
#define BK 64
#define NTILE 10
#define NPAIRS 130816.0f

__device__ __forceinline__ ushort f2bf(float f) {
    uint32_t u = __float_as_uint(f);
    uint32_t r = (u + 0x7fffu + ((u >> 16) & 1u)) >> 16;
    return (ushort)r;
}

__global__ __launch_bounds__(256) void gemm_kernel(
    const float* __restrict__ e, const float* __restrict__ a,
    const float* __restrict__ c, float* __restrict__ P) {
    int tile = blockIdx.x / KSPLIT;
    int ks   = blockIdx.x % KSPLIT;
    // map linear tile -> (ti, tj) upper triangle, ti <= tj, 4x4 tile grid
    int ti = 0, rem = tile;
    while (rem >= 4 - ti) { rem -= 4 - ti; ++ti; }
    int tj = ti + rem;
    const int brow = ti * 128, bcol = tj * 128;

    const int kbase = ks * KCHUNK;
    const int field = kbase / DFIELD;
    const int koff0 = kbase % DFIELD;
    const float* X = (field == 0) ? e : ((field == 1) ? a : c);

    __shared__ ushort As[128 * 64];
    __shared__ ushort Bs[128 * 64];

    const int t = threadIdx.x;
    const int lane = t & 63, wid = t >> 6;
    const int wr = (wid >> 1) * 64, wc = (wid & 1) * 64;
    const int srow = t >> 3;          // 0..31
    const int scg  = (t & 7) * 8;     // k offset within BK, 8-elem groups

    const f32x4 zero = {0.f, 0.f, 0.f, 0.f};
    f32x4 acc[4][4];
#pragma unroll
    for (int m = 0; m < 4; ++m)
#pragma unroll
        for (int n = 0; n < 4; ++n) acc[m][n] = zero;

    const float* pa = X + (size_t)(brow + srow) * DFIELD + koff0 + scg;
    const float* pb = X + (size_t)(bcol + srow) * DFIELD + koff0 + scg;

    for (int kt = 0; kt < KCHUNK / BK; ++kt) {
        const int kk = kt * BK;
        // ---- stage A ----
#pragma unroll
        for (int rep = 0; rep < 4; ++rep) {
            const int r = srow + rep * 32;
            const float* p = pa + (size_t)(rep * 32) * DFIELD + kk;
            float4 v0 = reinterpret_cast<const float4*>(p)[0];
            float4 v1 = reinterpret_cast<const float4*>(p)[1];
            short8 w;
            w[0] = (short)f2bf(v0.x); w[1] = (short)f2bf(v0.y);
            w[2] = (short)f2bf(v0.z); w[3] = (short)f2bf(v0.w);
            w[4] = (short)f2bf(v1.x); w[5] = (short)f2bf(v1.y);
            w[6] = (short)f2bf(v1.z); w[7] = (short)f2bf(v1.w);
            const int g = (scg >> 3) ^ (r & 7);
            *reinterpret_cast<short8*>(&As[r * 64 + g * 8]) = w;
        }
        // ---- stage B ----
#pragma unroll
        for (int rep = 0; rep < 4; ++rep) {
            const int r = srow + rep * 32;
            const float* p = pb + (size_t)(rep * 32) * DFIELD + kk;
            float4 v0 = reinterpret_cast<const float4*>(p)[0];
            float4 v1 = reinterpret_cast<const float4*>(p)[1];
            short8 w;
            w[0] = (short)f2bf(v0.x); w[1] = (short)f2bf(v0.y);
            w[2] = (short)f2bf(v0.z); w[3] = (short)f2bf(v0.w);
            w[4] = (short)f2bf(v1.x); w[5] = (short)f2bf(v1.y);
            w[6] = (short)f2bf(v1.z); w[7] = (short)f2bf(v1.w);
            const int g = (scg >> 3) ^ (r & 7);
            *reinterpret_cast<short8*>(&Bs[r * 64 + g * 8]) = w;
        }
        __syncthreads();
        // ---- compute ----
#pragma unroll
        for (int half = 0; half < 2; ++half) {
            short8 af[4], bfv[4];
            const int kq = half * 4 + (lane >> 4);  // 16B granule index (pre-swizzle)
#pragma unroll
            for (int m = 0; m < 4; ++m) {
                const int row = wr + m * 16 + (lane & 15);
                const int g = kq ^ (row & 7);
                af[m] = *reinterpret_cast<const short8*>(&As[row * 64 + g * 8]);
            }
#pragma unroll
            for (int n = 0; n < 4; ++n) {
                const int row = wc + n * 16 + (lane & 15);
                const int g = kq ^ (row & 7);
                bfv[n] = *reinterpret_cast<const short8*>(&Bs[row * 64 + g * 8]);
            }
#pragma unroll
            for (int m = 0; m < 4; ++m)
#pragma unroll
                for (int n = 0; n < 4; ++n)
                    acc[m][n] = __builtin_amdgcn_mfma_f32_16x16x32_bf16(
                        af[m], bfv[n], acc[m][n], 0, 0, 0);
        }
        __syncthreads();
    }

    // ---- write split-K partials (deterministic, no atomics) ----
    float* Pk = P + ((size_t)ks << 18);
    const int ci = (lane >> 4) * 4;  // C/D layout: row = (lane>>4)*4 + reg
    const int cj = lane & 15;        //             col = lane & 15
#pragma unroll
    for (int m = 0; m < 4; ++m)
#pragma unroll
        for (int n = 0; n < 4; ++n)
#pragma unroll
            for (int r = 0; r < 4; ++r) {
                const int gi = brow + wr + m * 16 + ci + r;
                const int gj = bcol + wc + n * 16 + cj;
                Pk[(size_t)gi * BSZ + gj] = acc[m][n][r];
            }
}

__global__ void diag_kernel(const float* __restrict__ P, float* __restrict__ DIAG) {
    int i = blockIdx.x * blockDim.x + threadIdx.x;
    if (i < BSZ) {
        float s = 0.f;
#pragma unroll
        for (int k = 0; k < KSPLIT; ++k)
            s += P[((size_t)k << 18) + (size_t)i * BSZ + i];
        DIAG[i] = s;
    }
}

__global__ void pair_kernel(const float* __restrict__ P, const float* __restrict__ DIAG,
                            const int* __restrict__ tg, float* __restrict__ LP) {
    const int t = threadIdx.x;
    const int bid = blockIdx.x;
    float local = 0.f;
    for (int p = bid * 256 + t; p < BSZ * BSZ; p += 256 * 256) {
        const int i = p >> 9, j = p & 511;
        if (i < j) {
            float g = 0.f;
#pragma unroll
            for (int k = 0; k < KSPLIT; ++k)
                g += P[((size_t)k << 18) + p];
            const float d = (DIAG[i] + DIAG[j] - 2.f * g) * (1.f / 16384.f);
            local += (tg[i] == tg[j]) ? d : fmaxf(1.f - d, 0.f);
        }
    }
#pragma unroll
    for (int off = 32; off; off >>= 1) local += __shfl_down(local, off, 64);
    __shared__ float red[4];
    const int lane = t & 63, wid = t >> 6;
    if (lane == 0) red[wid] = local;
    __syncthreads();
    if (t == 0) LP[bid] = red[0] + red[1] + red[2] + red[3];
}

__global__ void final_kernel(const float* __restrict__ LP, float* __restrict__ out) {
    const int t = threadIdx.x;
    float v = LP[t];
#pragma unroll
    for (int off = 32; off; off >>= 1) v += __shfl_down(v, off, 64);
    __shared__ float red[4];
    if ((t & 63) == 0) red[t >> 6] = v;
    __syncthreads();
    if (t == 0) out[0] = (red[0] + red[1] + red[2] + red[3]) * (1.f / NPAIRS);
}

extern "C" void kernel_launch(void* const* d_in, const int* in_sizes, int n_in,
                              void* d_out, int out_size, void* d_ws, size_t ws_size,
                              hipStream_t stream) {
    const float* e  = (const float*)d_in[0];
    const float* a  = (const float*)d_in[1];
    const float* c  = (const float*)d_in[2];
    const int*   tg = (const int*)d_in[3];

    float* P    = (float*)d_ws;                                   // 48 MiB partials
    float* DIAG = (float*)((char*)d_ws + (size_t)KSPLIT * BSZ * BSZ * 4);
    float* LP   = DIAG + BSZ;
    float* out  = (float*)d_out;

    gemm_kernel<<<dim3(NTILE * KSPLIT), dim3(256), 0, stream>>>(e, a, c, P);
    diag_kernel<<<dim3(2), dim3(256), 0, stream>>>(P, DIAG);
    pair_kernel<<<dim3(256), dim3(256), 0, stream>>>(P, DIAG, tg, LP);
    final_kernel<<<dim3(1), dim3(256), 0, stream>>>(LP, out);
}